// Round 1
// baseline (44.536 us; speedup 1.0000x reference)
//
#include <hip/hip_runtime.h>

// Problem: inputs [B=4096, F=64, D=128] f32.
// out[b, f*D + d] = x[b,f,d] * (sum_f' x[b,f',d]) - x[b,f,d]^2
//                 = x * (colsum - x)
//
// One block per batch. 256 threads * 8 float4 = 2048 float4 = 8192 floats = one batch.
// Thread t's elements are at float4-linear indices t + 256k -> all share the same
// float4-column group (t & 31), so its 8-vector sum is a column partial covering
// rows (t>>5) + 8k. LDS reduce across the 8 row-groups, then emit.

#define B_TOTAL 4096
#define F_FIELDS 64
#define D_DIM 128
#define VEC_PER_BATCH 2048   // 64*128/4

__global__ __launch_bounds__(256) void fm_cross_kernel(
    const float4* __restrict__ in, float4* __restrict__ out) {
  __shared__ float4 psums[256];  // 4 KiB

  const int t = threadIdx.x;
  const size_t base = (size_t)blockIdx.x * VEC_PER_BATCH;

  // Load 8 float4 per thread (coalesced: consecutive lanes -> consecutive 16B).
  float4 v[8];
#pragma unroll
  for (int k = 0; k < 8; ++k) {
    v[k] = in[base + t + 256 * k];
  }

  // Per-thread partial column sum (all 8 vectors share column group t&31).
  float4 p = v[0];
#pragma unroll
  for (int k = 1; k < 8; ++k) {
    p.x += v[k].x; p.y += v[k].y; p.z += v[k].z; p.w += v[k].w;
  }
  psums[t] = p;
  __syncthreads();

  // Full column sum: combine the 8 row-group partials for this column group.
  // Read pattern: lanes 0..31 hit consecutive float4 (banks spread), lanes
  // 32..63 read identical addresses (broadcast / free 2-way aliasing).
  const int d4 = t & 31;
  float4 s = psums[d4];
#pragma unroll
  for (int r = 1; r < 8; ++r) {
    float4 q = psums[d4 + 32 * r];
    s.x += q.x; s.y += q.y; s.z += q.z; s.w += q.w;
  }

  // Emit x * (colsum - x), coalesced.
#pragma unroll
  for (int k = 0; k < 8; ++k) {
    float4 x = v[k];
    float4 o;
    o.x = x.x * (s.x - x.x);
    o.y = x.y * (s.y - x.y);
    o.z = x.z * (s.z - x.z);
    o.w = x.w * (s.w - x.w);
    out[base + t + 256 * k] = o;
  }
}

extern "C" void kernel_launch(void* const* d_in, const int* in_sizes, int n_in,
                              void* d_out, int out_size, void* d_ws, size_t ws_size,
                              hipStream_t stream) {
  const float4* in = (const float4*)d_in[0];
  float4* out = (float4*)d_out;
  const int batches = in_sizes[0] / (F_FIELDS * D_DIM);  // 4096
  fm_cross_kernel<<<batches, 256, 0, stream>>>(in, out);
}

// Round 3
// 43.886 us; speedup vs baseline: 1.0148x; 1.0148x over previous
//
#include <hip/hip_runtime.h>

// Problem: inputs [B=4096, F=64, D=128] f32.
// out[b, f*D + d] = x[b,f,d] * (sum_f' x[b,f',d]) - x[b,f,d]^2
//                 = x * (colsum - x)
//
// One block per batch. 256 threads * 8 float4 = 2048 float4 = 8192 floats = one batch.
// Thread t's elements are at float4-linear indices t + 256k -> all share the same
// float4-column group (t & 31), so its 8-vector sum is a column partial covering
// rows (t>>5) + 8k. LDS reduce across the 8 row-groups, then emit.
//
// Round 3: non-temporal output stores via clang native vector type
// (__builtin_nontemporal_store rejects HIP_vector_type float4). Goal: keep
// the 128 MiB input L3-resident by not write-allocating the 128 MiB output.

#define F_FIELDS 64
#define D_DIM 128
#define VEC_PER_BATCH 2048   // 64*128/4

typedef float f32x4 __attribute__((ext_vector_type(4)));

__global__ __launch_bounds__(256) void fm_cross_kernel(
    const f32x4* __restrict__ in, f32x4* __restrict__ out) {
  __shared__ f32x4 psums[256];  // 4 KiB

  const int t = threadIdx.x;
  const size_t base = (size_t)blockIdx.x * VEC_PER_BATCH;

  // Load 8 float4 per thread (coalesced: consecutive lanes -> consecutive 16B).
  f32x4 v[8];
#pragma unroll
  for (int k = 0; k < 8; ++k) {
    v[k] = in[base + t + 256 * k];
  }

  // Per-thread partial column sum (all 8 vectors share column group t&31).
  f32x4 p = v[0];
#pragma unroll
  for (int k = 1; k < 8; ++k) {
    p += v[k];
  }
  psums[t] = p;
  __syncthreads();

  // Full column sum: combine the 8 row-group partials for this column group.
  // Lanes 0..31 read consecutive float4 (banks spread); lanes 32..63 read the
  // same addresses (broadcast / free 2-way aliasing).
  const int d4 = t & 31;
  f32x4 s = psums[d4];
#pragma unroll
  for (int r = 1; r < 8; ++r) {
    s += psums[d4 + 32 * r];
  }

  // Emit x * (colsum - x), coalesced, non-temporal (don't pollute L2/L3).
#pragma unroll
  for (int k = 0; k < 8; ++k) {
    f32x4 x = v[k];
    f32x4 o = x * (s - x);
    __builtin_nontemporal_store(o, &out[base + t + 256 * k]);
  }
}

extern "C" void kernel_launch(void* const* d_in, const int* in_sizes, int n_in,
                              void* d_out, int out_size, void* d_ws, size_t ws_size,
                              hipStream_t stream) {
  const f32x4* in = (const f32x4*)d_in[0];
  f32x4* out = (f32x4*)d_out;
  const int batches = in_sizes[0] / (F_FIELDS * D_DIM);  // 4096
  fm_cross_kernel<<<batches, 256, 0, stream>>>(in, out);
}